// Round 17
// baseline (5556.925 us; speedup 1.0000x reference)
//
#include <hip/hip_runtime.h>
#include <hip/hip_bf16.h>

// ---------------- sizes ----------------
#define H    400
#define SEG  416          // per-layer feature segment, padded to 13*32
#define G4   1600
#define TT   1024
#define BB   64
#define NOUT 121
#define KS0  13
#define KS12 26
#define FPAD 1248         // 3*SEG
#define KSL  39
#define NG   25           // producer slots per flag group
#define ROWSL 78          // exchange units per row: 25 granule-triples + 3 pad

typedef __attribute__((ext_vector_type(8))) short bf16x8;
typedef __attribute__((ext_vector_type(4))) float f32x4;
typedef __attribute__((ext_vector_type(4))) int   i32x4;
typedef unsigned short u16;

// ---------------- persistent device state ----------------
__device__ __align__(16) u16   g_outs[BB * TT][FPAD];   // inter-layer + final GEMM A
// self-h exchange (R9 geometry, refchecked): 16B units {6 bf16 cols, pad, version}
// [l][mtile][parity][(row*ROWSL + jt*3 + j) * 4 ints]
__device__ __align__(16) int   g_ex[3][4][2][16 * ROWSL * 4];
__device__ __align__(16) u16   g_pk0[100][KS0][512];
__device__ __align__(16) u16   g_pk1[100][KS12][512];
__device__ __align__(16) u16   g_pk2[100][KS12][512];
__device__ __align__(16) u16   g_pkl[8][KSL][512];
__device__ float g_bsum[3][G4];
__device__ float g_wx[3][G4][3];
__device__ float g_bl[128];
// flags: one slot per 128B line (bank-spread). g_f = self-chain (fired, no drain),
// g_fo = inter-layer (guards g_outs rows; [0]=l0 outs, [1]=l1 outs).
__device__ __align__(128) int g_f[3][4][32][32];
__device__ __align__(128) int g_fo[2][4][32][32];
__device__ int   g_abort;

// ---------------- helpers ----------------
__device__ inline u16 f2b(float f) {
  union { float f; unsigned u; } v; v.f = f;
  unsigned r = v.u + 0x7FFF + ((v.u >> 16) & 1);
  return (u16)(r >> 16);
}
__device__ inline float sigm(float x) { return 1.f / (1.f + __expf(-x)); }
__device__ inline float tanh_(float x) { return 2.f * sigm(2.f * x) - 1.f; }

// device-scope (Agent) accessors, cross-XCD coherent (verified R12)
__device__ inline void st16_s(u16* p, unsigned v) {
  asm volatile("global_store_short %0, %1, off sc1" :: "v"(p), "v"(v) : "memory");
}
__device__ inline void st32_s(int* p, int v) {
  asm volatile("global_store_dword %0, %1, off sc1" :: "v"(p), "v"(v) : "memory");
}
__device__ inline int poll_s(const int* p) {
  int v;
  asm volatile("global_load_dword %0, %1, off sc1\n\ts_waitcnt vmcnt(0)"
               : "=v"(v) : "v"(p) : "memory");
  return v;
}
// wave-cooperative wait over bank-spread slots: all NG slots >= tv (skip exempt)
template <int SLEEP>
__device__ inline int wait_line(const int (*line)[32], int tv, int skip) {
  const int slot = threadIdx.x & 31;
  const bool act = (slot < NG) && (slot != skip);
  const int* p = &line[act ? slot : 0][0];
  long n = 0;
  for (;;) {
    int v = poll_s(p);
    if (__all((!act) || (v >= tv))) return 0;
    if (SLEEP) __builtin_amdgcn_s_sleep(2);
    if ((++n & 255) == 0) {
      if (poll_s(&g_abort)) return 1;
      if (n > (1L << 21)) { st32_s(&g_abort, 1); return 1; }
    }
  }
}

// ---- validated exchange consume (R9 geometry, refchecked): rounds of 26 loads,
// version check, register-select fragment build + MFMA. Called AFTER flag spin,
// so typically exactly one round. 1 = abort.
__device__ __forceinline__ int consume_ex(const int* bp, int tv, int padl, int odd,
                                          const bf16x8 Bf[4][13], f32x4 acc[4]) {
  i32x4 va[13], vb[13];
  long rounds = 0; int ab = 0;
  for (;;) {
#define EXLD(K, O0, O1) \
    asm volatile("global_load_dwordx4 %0, %2, off offset:" O0 " sc1\n\t" \
                 "global_load_dwordx4 %1, %2, off offset:" O1 " sc1" \
                 : "=v"(va[K]), "=v"(vb[K]) : "v"(bp) : "memory");
    EXLD(0,"0","16")      EXLD(1,"96","112")    EXLD(2,"192","208")
    EXLD(3,"288","304")   EXLD(4,"384","400")   EXLD(5,"480","496")
    EXLD(6,"576","592")   EXLD(7,"672","688")   EXLD(8,"768","784")
    EXLD(9,"864","880")   EXLD(10,"960","976")  EXLD(11,"1056","1072")
    EXLD(12,"1152","1168")
#undef EXLD
    asm volatile("s_waitcnt vmcnt(0)" ::: "memory");
    __builtin_amdgcn_sched_barrier(0);
    int okv = 1;
#pragma unroll
    for (int k = 0; k < 13; ++k) {
      int o = (va[k][3] == tv) & (vb[k][3] == tv);
      if (k == 12) o |= padl;     // pad units: permanently zero, payload unused
      okv &= o;
    }
    if (__all(okv)) break;
    if ((++rounds & 31) == 0) {
      if (poll_s(&g_abort)) { ab = 1; break; }
      if (rounds > (1L << 16)) { st32_s(&g_abort, 1); ab = 1; break; }
    }
  }
  if (ab) return 1;
#pragma unroll
  for (int k = 0; k < 13; ++k) {
    union { i32x4 i; bf16x8 h; } u;
    u.i[0] = odd ? va[k][1] : va[k][0];
    u.i[1] = odd ? va[k][2] : va[k][1];
    u.i[2] = odd ? vb[k][0] : va[k][2];
    u.i[3] = odd ? vb[k][1] : vb[k][0];
#pragma unroll
    for (int g = 0; g < 4; ++g)
      acc[g] = __builtin_amdgcn_mfma_f32_16x16x32_bf16(u.h, Bf[g][k], acc[g], 0, 0, 0);
  }
  return 0;
}

// ---- producer (R9, refchecked): LDS transpose, 48 x 16B versioned unit stores,
// all fire-and-forget (NO drain)
__device__ __forceinline__ void produce_ex(int* exw, int jt, int t,
                                           const unsigned hb[4],
                                           u16 (*T)[18], int lane, int kg) {
  const int brow = lane & 15;
  T[kg * 4 + 0][brow] = (u16)hb[0];
  T[kg * 4 + 1][brow] = (u16)hb[1];
  T[kg * 4 + 2][brow] = (u16)hb[2];
  T[kg * 4 + 3][brow] = (u16)hb[3];
  asm volatile("s_waitcnt lgkmcnt(0)" ::: "memory");
  __builtin_amdgcn_sched_barrier(0);
  if (lane < 48) {
    int r = lane / 3, j = lane - r * 3;
    unsigned d0 = *(const unsigned*)&T[r][j * 6];
    unsigned d1 = *(const unsigned*)&T[r][j * 6 + 2];
    unsigned d2 = *(const unsigned*)&T[r][j * 6 + 4];
    i32x4 sv; sv[0] = (int)d0; sv[1] = (int)d1; sv[2] = (int)d2; sv[3] = t + 1;
    int* ep = exw + (r * ROWSL + jt * 3 + j) * 4;
    asm volatile("global_store_dwordx4 %0, %1, off sc1" :: "v"(ep), "v"(sv) : "memory");
  }
}

// ---------------- setup kernels ----------------
__global__ void k_zero() {
  int i = blockIdx.x * blockDim.x + threadIdx.x;
  if (i == 0) g_abort = 0;
  if (i < 3 * 4 * 32 * 32) (&g_f[0][0][0][0])[i] = 0;
  if (i < 2 * 4 * 32 * 32) (&g_fo[0][0][0][0])[i] = 0;
  if (i < 3 * 4 * 2 * 16 * ROWSL * 4) (&g_ex[0][0][0][0])[i] = 0;
  if (i < BB * TT * 24) {                  // zero pad columns of g_outs
    int r = i / 24, j = i % 24;
    int seg = j >> 3, w = j & 7;
    *(unsigned*)&g_outs[r][seg * SEG + 400 + w * 2] = 0u;
  }
}

__global__ void k_pack_rec(const float* Wih, const float* Whh, int layer,
                           int ksteps, int kin) {
  int i = blockIdx.x * blockDim.x + threadIdx.x;
  int total = 100 * ksteps * 512;
  if (i >= total) return;
  int j = i & 7, lane = (i >> 3) & 63;
  int ks = (i >> 9) % ksteps, nt = (i >> 9) / ksteps;
  int g = nt / 25, jt = nt % 25;
  int n  = g * 400 + jt * 16 + (lane & 15);
  int kk = (lane >> 4) * 8 + j;
  float v = 0.f;
  if (layer == 0) {
    int k = ks * 32 + kk;
    if (k < H) v = Whh[n * H + k];
  } else {
    if (ks < KS0) { int k = ks * 32 + kk;         if (k < H) v = Wih[n * kin + 3 + k]; }
    else          { int k = (ks - KS0) * 32 + kk; if (k < H) v = Whh[n * H + k]; }
  }
  u16* dst = (layer == 0) ? &g_pk0[0][0][0] : (layer == 1 ? &g_pk1[0][0][0] : &g_pk2[0][0][0]);
  dst[i] = f2b(v);
}

__global__ void k_pack_wl(const float* Wl, const float* bl) {
  int i = blockIdx.x * blockDim.x + threadIdx.x;
  if (i < 128) g_bl[i] = (i < NOUT) ? bl[i] : 0.f;
  int total = 8 * KSL * 512;
  if (i >= total) return;
  int j = i & 7, lane = (i >> 3) & 63;
  int ks = (i >> 9) % KSL, nt = (i >> 9) / KSL;
  int n = nt * 16 + (lane & 15);
  int k = ks * 32 + (lane >> 4) * 8 + j;
  int seg = k / SEG, jj = k - seg * SEG;
  float v = 0.f;
  if (n < NOUT && jj < 400) v = Wl[n * 1200 + seg * 400 + jj];
  (&g_pkl[0][0][0])[i] = f2b(v);
}

__global__ void k_pack_misc(const float* Wih0, const float* bih0, const float* bhh0,
                            const float* Wih1, const float* bih1, const float* bhh1,
                            const float* Wih2, const float* bih2, const float* bhh2) {
  int i = blockIdx.x * blockDim.x + threadIdx.x;
  if (i >= 3 * G4) return;
  int l = i / G4, n = i % G4;
  const float* bi = l == 0 ? bih0 : (l == 1 ? bih1 : bih2);
  const float* bh = l == 0 ? bhh0 : (l == 1 ? bhh1 : bhh2);
  const float* wi = l == 0 ? Wih0 : (l == 1 ? Wih1 : Wih2);
  int kin = l == 0 ? 3 : 403;
  g_bsum[l][n] = bi[n] + bh[n];
  for (int c = 0; c < 3; ++c) g_wx[l][n][c] = wi[n * kin + c];
}

// ---------------- persistent LSTM: zero-drain producer + flag spin + one
// validated consume round ----------------
// 125 WGs: l0 = 25 WGs (4 autonomous waves); l1/l2 = 50 WGs each (2 pairs x
// {kh=0 inter-wave (fo flags), kh=1 self-wave (exchange)}; one barrier/step
// LDS split-K join; epilogue duplicated).
__global__ __launch_bounds__(256, 1) void k_lstm(const float* __restrict__ X) {
  const int wg = blockIdx.x;
  int l, w2;
  if (wg < 25)      { l = 0; w2 = wg; }
  else if (wg < 75) { l = 1; w2 = wg - 25; }
  else              { l = 2; w2 = wg - 75; }

  const int tid = threadIdx.x;
  const int lane = tid & 63;
  const int wv = tid >> 6;
  const int brow = lane & 15;
  const int kg = lane >> 4;
  const int padl = (kg >= 2);
  const int odd = (kg & 1);

  int jt, mtile, kh, pair;
  if (l == 0) { jt = w2; mtile = wv; kh = 1; pair = 0; }
  else { int bg = w2 & 1; jt = w2 >> 1; kh = wv & 1; pair = wv >> 1; mtile = bg * 2 + pair; }
  const int jh = jt * 16 + brow;

  const u16* pk = (l == 0) ? &g_pk0[0][0][0] : (l == 1 ? &g_pk1[0][0][0] : &g_pk2[0][0][0]);
  const int nks = (l == 0) ? KS0 : KS12;
  const int wks0 = (l == 0) ? 0 : kh * 13;

  bf16x8 Bf[4][13];
#pragma unroll
  for (int g = 0; g < 4; ++g)
#pragma unroll
    for (int j = 0; j < 13; ++j)
      Bf[g][j] = *(const bf16x8*)&pk[(((g * 25 + jt) * nks + wks0 + j) * 64 + lane) * 8];

  float bsum[4], wxc[4][3];
#pragma unroll
  for (int g = 0; g < 4; ++g) {
    int n = g * 400 + jh;
    bsum[g] = g_bsum[l][n];
    wxc[g][0] = g_wx[l][n][0];
    wxc[g][1] = g_wx[l][n][1];
    wxc[g][2] = g_wx[l][n][2];
  }
  float cst[4] = {0.f, 0.f, 0.f, 0.f};
  const int exlane = (brow * ROWSL + (kg >> 1) * 3 + (kg & 1)) * 4;

  __shared__ float red[2][2][2][64][20];   // [pair][parity][kh][lane][16+pad]
  __shared__ __align__(16) u16 T[4][16][18];
  __shared__ int s_ab[2][4];

#define GLS(i, OFF) asm volatile("global_load_dwordx4 %0, %1, off offset:" OFF " sc1" \
                                 : "=v"(A[i]) : "v"(rowp))
#define GLS_ALL GLS(0,"0");GLS(1,"64");GLS(2,"128");GLS(3,"192");GLS(4,"256");GLS(5,"320"); \
                GLS(6,"384");GLS(7,"448");GLS(8,"512");GLS(9,"576");GLS(10,"640");          \
                GLS(11,"704");GLS(12,"768")
#define XGATE(xg) { \
  _Pragma("unroll") \
  for (int r = 0; r < 4; ++r) { \
    int row = mtile * 16 + kg * 4 + r; \
    const float* xp = X + ((long)row * TT + t) * 3; \
    float x0 = xp[0], x1 = xp[1], x2 = xp[2]; \
    _Pragma("unroll") \
    for (int g = 0; g < 4; ++g) \
      xg[g][r] = bsum[g] + wxc[g][0] * x0 + wxc[g][1] * x1 + wxc[g][2] * x2; \
  } }
#define MFMA_ALL { asm volatile("s_waitcnt vmcnt(0)" ::: "memory"); \
  __builtin_amdgcn_sched_barrier(0); \
  _Pragma("unroll") \
  for (int j = 0; j < 13; ++j) \
    _Pragma("unroll") \
    for (int g = 0; g < 4; ++g) \
      acc[g] = __builtin_amdgcn_mfma_f32_16x16x32_bf16(A[j], Bf[g][j], acc[g], 0, 0, 0); }

  if (l == 0) {
    // ===== layer 0: autonomous waves; flag spin + validated consume; zero-drain =====
    for (int t = 0; t < TT; ++t) {
      float xg[4][4];
      XGATE(xg);
      f32x4 acc[4] = {};
      if (t > 0) {
        if (wait_line<0>(g_f[0][mtile], t, jt)) return;
        // spin's vmcnt(0) drained outs(t-1) stores -> certify rows 0..t-1
        if (lane == 0) st32_s(&g_fo[0][mtile][jt][0], t);
        const int* bp = &g_ex[0][mtile][(t - 1) & 1][exlane];
        if (consume_ex(bp, t, padl, odd, Bf, acc)) return;
      }
      unsigned hb[4];
#pragma unroll
      for (int r = 0; r < 4; ++r) {
        float gate[4];
#pragma unroll
        for (int g = 0; g < 4; ++g) gate[g] = acc[g][r] + xg[g][r];
        float ig = sigm(gate[0]), fg = sigm(gate[1]);
        float gg = tanh_(gate[2]), og = sigm(gate[3]);
        float c = fg * cst[r] + ig * gg;
        cst[r] = c;
        hb[r] = (unsigned)f2b(og * tanh_(c));
      }
      produce_ex(&g_ex[0][mtile][t & 1][0], jt, t, hb, T[wv], lane, kg);
      if (lane == 0) st32_s(&g_f[0][mtile][jt][0], t + 1);   // fired, no drain
#pragma unroll
      for (int r = 0; r < 4; ++r)                            // fire-and-forget
        st16_s(&g_outs[(long)(mtile * 16 + kg * 4 + r) * TT + t][jh], hb[r]);
    }
    asm volatile("s_waitcnt vmcnt(0)" ::: "memory");
    if (lane == 0) st32_s(&g_fo[0][mtile][jt][0], TT);
    return;
  }

  // ===== layers 1/2: pairs {kh=0 inter-wave, kh=1 self-wave}, 1 barrier/step =====
  for (int t = 0; t < TT; ++t) {
    float xg[4][4];
    XGATE(xg);

    int ab = 0;
    f32x4 acc[4] = {};
    if (kh) {
      if (t > 0) {
        ab = wait_line<0>(g_f[l][mtile], t, jt);
        if (!ab) {
          const int* bp = &g_ex[l][mtile][(t - 1) & 1][exlane];
          ab = consume_ex(bp, t, padl, odd, Bf, acc);
        }
      }
    } else {
      ab = wait_line<1>(g_fo[l - 1][mtile], t + 1, -1);
      if (!ab) {
        // wait's vmcnt(0) drained own outs(t-1) stores -> certify (l==1 feeds l2)
        if (l == 1 && t > 0 && lane == 0) st32_s(&g_fo[1][mtile][jt][0], t);
        const u16* rowp = &g_outs[(long)(mtile * 16 + brow) * TT + t][(l - 1) * SEG + kg * 8];
        bf16x8 A[13];
        GLS_ALL;
        MFMA_ALL;
      }
    }
    if (lane == 0) s_ab[t & 1][wv] = ab;

    // deposit own partial; single barrier; join with peer's
#pragma unroll
    for (int g = 0; g < 4; ++g)
      *(f32x4*)&red[pair][t & 1][kh][lane][g * 4] = acc[g];
    __syncthreads();
    if (s_ab[t & 1][0] | s_ab[t & 1][1] | s_ab[t & 1][2] | s_ab[t & 1][3]) return;
    f32x4 gacc[4];
#pragma unroll
    for (int g = 0; g < 4; ++g)
      gacc[g] = acc[g] + *(const f32x4*)&red[pair][t & 1][kh ^ 1][lane][g * 4];

    // epilogue duplicated on both waves (identical fp -> identical bits)
    unsigned hb[4];
#pragma unroll
    for (int r = 0; r < 4; ++r) {
      float gate[4];
#pragma unroll
      for (int g = 0; g < 4; ++g) gate[g] = gacc[g][r] + xg[g][r];
      float ig = sigm(gate[0]), fg = sigm(gate[1]);
      float gg = tanh_(gate[2]), og = sigm(gate[3]);
      float c = fg * cst[r] + ig * gg;
      cst[r] = c;
      hb[r] = (unsigned)f2b(og * tanh_(c));
    }

    if (kh) {
      // critical wave: fire versioned units + flag, NO drain
      produce_ex(&g_ex[l][mtile][t & 1][0], jt, t, hb, T[wv], lane, kg);
      if (lane == 0) st32_s(&g_f[l][mtile][jt][0], t + 1);
    } else {
      // slack wave: outs stores fire-and-forget (drained by next wait's vmcnt)
#pragma unroll
      for (int r = 0; r < 4; ++r)
        st16_s(&g_outs[(long)(mtile * 16 + kg * 4 + r) * TT + t][l * SEG + jh], hb[r]);
    }
  }
  if (!kh && l == 1) {
    asm volatile("s_waitcnt vmcnt(0)" ::: "memory");
    if (lane == 0) st32_s(&g_fo[1][mtile][jt][0], TT);
  }
#undef GLS
#undef GLS_ALL
#undef XGATE
#undef MFMA_ALL
}

// ---------------- final projection: [65536,1248] x [1248,128] ----------------
__global__ __launch_bounds__(256) void k_final(float* __restrict__ out) {
  int mt   = blockIdx.x * 4 + (threadIdx.x >> 6);
  int lane = threadIdx.x & 63;
  int arow = mt * 16 + (lane & 15);
  int kchunk = (lane >> 4) * 8;
  f32x4 acc[8] = {};
  for (int ks = 0; ks < KSL; ++ks) {
    bf16x8 a = *(const bf16x8*)&g_outs[arow][ks * 32 + kchunk];
#pragma unroll
    for (int nt = 0; nt < 8; ++nt) {
      bf16x8 b = *(const bf16x8*)&g_pkl[nt][ks][lane * 8];
      acc[nt] = __builtin_amdgcn_mfma_f32_16x16x32_bf16(a, b, acc[nt], 0, 0, 0);
    }
  }
#pragma unroll
  for (int nt = 0; nt < 8; ++nt) {
    int o = nt * 16 + (lane & 15);
    if (o >= NOUT) continue;
#pragma unroll
    for (int r = 0; r < 4; ++r) {
      int m = mt * 16 + (lane >> 4) * 4 + r;
      out[(long)m * NOUT + o] = acc[nt][r] + g_bl[o];
    }
  }
}

// ---------------- launch ----------------
extern "C" void kernel_launch(void* const* d_in, const int* in_sizes, int n_in,
                              void* d_out, int out_size, void* d_ws, size_t ws_size,
                              hipStream_t stream) {
  const float* X    = (const float*)d_in[0];
  const float* Wih0 = (const float*)d_in[1];
  const float* Whh0 = (const float*)d_in[2];
  const float* bih0 = (const float*)d_in[3];
  const float* bhh0 = (const float*)d_in[4];
  const float* Wih1 = (const float*)d_in[5];
  const float* Whh1 = (const float*)d_in[6];
  const float* bih1 = (const float*)d_in[7];
  const float* bhh1 = (const float*)d_in[8];
  const float* Wih2 = (const float*)d_in[9];
  const float* Whh2 = (const float*)d_in[10];
  const float* bih2 = (const float*)d_in[11];
  const float* bhh2 = (const float*)d_in[12];
  const float* Wl   = (const float*)d_in[13];
  const float* bl   = (const float*)d_in[14];

  k_zero<<<(BB * TT * 24 + 255) / 256, 256, 0, stream>>>();
  k_pack_rec<<<(100 * KS0  * 512 + 255) / 256, 256, 0, stream>>>(nullptr, Whh0, 0, KS0, 3);
  k_pack_rec<<<(100 * KS12 * 512 + 255) / 256, 256, 0, stream>>>(Wih1, Whh1, 1, KS12, 403);
  k_pack_rec<<<(100 * KS12 * 512 + 255) / 256, 256, 0, stream>>>(Wih2, Whh2, 2, KS12, 403);
  k_pack_wl<<<(8 * KSL * 512 + 255) / 256, 256, 0, stream>>>(Wl, bl);
  k_pack_misc<<<(3 * G4 + 255) / 256, 256, 0, stream>>>(Wih0, bih0, bhh0,
                                                        Wih1, bih1, bhh1,
                                                        Wih2, bih2, bhh2);
  k_lstm<<<125, 256, 0, stream>>>(X);
  k_final<<<1024, 256, 0, stream>>>((float*)d_out);
}

// Round 18
// 3555.597 us; speedup vs baseline: 1.5629x; 1.5629x over previous
//
#include <hip/hip_runtime.h>
#include <hip/hip_bf16.h>

// ---------------- sizes ----------------
#define H    400
#define SEG  416          // per-layer feature segment, padded to 13*32
#define G4   1600
#define TT   1024
#define BB   64
#define NOUT 121
#define KS0  13
#define KS12 26
#define FPAD 1248         // 3*SEG
#define KSL  39
#define NG   25           // producer slots per flag group

typedef __attribute__((ext_vector_type(8))) short bf16x8;
typedef __attribute__((ext_vector_type(4))) float f32x4;
typedef unsigned short u16;

// ---------------- persistent device state ----------------
__device__ __align__(16) u16   g_outs[BB * TT][FPAD];   // inter-layer + final GEMM A
__device__ __align__(16) u16   g_h[3][2][BB][SEG];      // self h, parity double buffer
__device__ __align__(16) u16   g_pk0[100][KS0][512];
__device__ __align__(16) u16   g_pk1[100][KS12][512];
__device__ __align__(16) u16   g_pk2[100][KS12][512];
__device__ __align__(16) u16   g_pkl[8][KSL][512];
__device__ float g_bsum[3][G4];
__device__ float g_wx[3][G4][3];
__device__ float g_bl[128];
// flags: one slot per 128B line (bank-spread). g_f = self-chain (guards g_h),
// g_fo = inter-layer (guards g_outs rows; [0]=l0 outs, [1]=l1 outs).
__device__ __align__(128) int g_f[3][4][32][32];
__device__ __align__(128) int g_fo[2][4][32][32];
__device__ int   g_abort;

// ---------------- helpers ----------------
__device__ inline u16 f2b(float f) {
  union { float f; unsigned u; } v; v.f = f;
  unsigned r = v.u + 0x7FFF + ((v.u >> 16) & 1);
  return (u16)(r >> 16);
}
__device__ inline float sigm(float x) { return 1.f / (1.f + __expf(-x)); }
__device__ inline float tanh_(float x) { return 2.f * sigm(2.f * x) - 1.f; }

// device-scope (Agent) accessors, cross-XCD coherent (verified R12)
__device__ inline void st16_s(u16* p, unsigned v) {
  asm volatile("global_store_short %0, %1, off sc1" :: "v"(p), "v"(v) : "memory");
}
__device__ inline void st32_s(int* p, int v) {
  asm volatile("global_store_dword %0, %1, off sc1" :: "v"(p), "v"(v) : "memory");
}
__device__ inline int poll_s(const int* p) {
  int v;
  asm volatile("global_load_dword %0, %1, off sc1\n\ts_waitcnt vmcnt(0)"
               : "=v"(v) : "v"(p) : "memory");
  return v;
}
// wave-cooperative wait over bank-spread slots: all NG slots >= tv (skip exempt)
template <int SLEEP>
__device__ inline int wait_line(const int (*line)[32], int tv, int skip) {
  const int slot = threadIdx.x & 31;
  const bool act = (slot < NG) && (slot != skip);
  const int* p = &line[act ? slot : 0][0];
  long n = 0;
  for (;;) {
    int v = poll_s(p);
    if (__all((!act) || (v >= tv))) return 0;
    if (SLEEP) __builtin_amdgcn_s_sleep(2);
    if ((++n & 255) == 0) {
      if (poll_s(&g_abort)) return 1;
      if (n > (1L << 21)) { st32_s(&g_abort, 1); return 1; }
    }
  }
}

// ---------------- setup kernels ----------------
__global__ void k_zero() {
  int i = blockIdx.x * blockDim.x + threadIdx.x;
  if (i == 0) g_abort = 0;
  if (i < 3 * 4 * 32 * 32) (&g_f[0][0][0][0])[i] = 0;
  if (i < 2 * 4 * 32 * 32) (&g_fo[0][0][0][0])[i] = 0;
  if (i < 3 * 2 * BB * SEG / 2) ((unsigned*)g_h)[i] = 0u;
  if (i < BB * TT * 24) {                  // zero pad columns of g_outs
    int r = i / 24, j = i % 24;
    int seg = j >> 3, w = j & 7;
    *(unsigned*)&g_outs[r][seg * SEG + 400 + w * 2] = 0u;
  }
}

__global__ void k_pack_rec(const float* Wih, const float* Whh, int layer,
                           int ksteps, int kin) {
  int i = blockIdx.x * blockDim.x + threadIdx.x;
  int total = 100 * ksteps * 512;
  if (i >= total) return;
  int j = i & 7, lane = (i >> 3) & 63;
  int ks = (i >> 9) % ksteps, nt = (i >> 9) / ksteps;
  int g = nt / 25, jt = nt % 25;
  int n  = g * 400 + jt * 16 + (lane & 15);
  int kk = (lane >> 4) * 8 + j;
  float v = 0.f;
  if (layer == 0) {
    int k = ks * 32 + kk;
    if (k < H) v = Whh[n * H + k];
  } else {
    if (ks < KS0) { int k = ks * 32 + kk;         if (k < H) v = Wih[n * kin + 3 + k]; }
    else          { int k = (ks - KS0) * 32 + kk; if (k < H) v = Whh[n * H + k]; }
  }
  u16* dst = (layer == 0) ? &g_pk0[0][0][0] : (layer == 1 ? &g_pk1[0][0][0] : &g_pk2[0][0][0]);
  dst[i] = f2b(v);
}

__global__ void k_pack_wl(const float* Wl, const float* bl) {
  int i = blockIdx.x * blockDim.x + threadIdx.x;
  if (i < 128) g_bl[i] = (i < NOUT) ? bl[i] : 0.f;
  int total = 8 * KSL * 512;
  if (i >= total) return;
  int j = i & 7, lane = (i >> 3) & 63;
  int ks = (i >> 9) % KSL, nt = (i >> 9) / KSL;
  int n = nt * 16 + (lane & 15);
  int k = ks * 32 + (lane >> 4) * 8 + j;
  int seg = k / SEG, jj = k - seg * SEG;
  float v = 0.f;
  if (n < NOUT && jj < 400) v = Wl[n * 1200 + seg * 400 + jj];
  (&g_pkl[0][0][0])[i] = f2b(v);
}

__global__ void k_pack_misc(const float* Wih0, const float* bih0, const float* bhh0,
                            const float* Wih1, const float* bih1, const float* bhh1,
                            const float* Wih2, const float* bih2, const float* bhh2) {
  int i = blockIdx.x * blockDim.x + threadIdx.x;
  if (i >= 3 * G4) return;
  int l = i / G4, n = i % G4;
  const float* bi = l == 0 ? bih0 : (l == 1 ? bih1 : bih2);
  const float* bh = l == 0 ? bhh0 : (l == 1 ? bhh1 : bhh2);
  const float* wi = l == 0 ? Wih0 : (l == 1 ? Wih1 : Wih2);
  int kin = l == 0 ? 3 : 403;
  g_bsum[l][n] = bi[n] + bh[n];
  for (int c = 0; c < 3; ++c) g_wx[l][n][c] = wi[n * kin + c];
}

// ---------------- persistent LSTM (R12 protocol, pair-private 128-thread WGs) ----------------
// 250 WGs x 128 threads:
//   0..49    l0: 2 autonomous waves (jt = wg>>1, mtile = (wg&1)*2 + wv), no barriers
//   50..149  l1: one split-K pair per WG (mtile = q&3, jt = q>>2, kh = wv)
//   150..249 l2: same
// Barrier now couples ONLY the 2 waves of one pair (R12 coupled 2 pairs).
// Deferred tail drains + bank-spread flags exactly as R12.
__global__ __launch_bounds__(128, 1) void k_lstm(const float* __restrict__ X) {
  const int wg = blockIdx.x;
  const int tid = threadIdx.x;
  const int lane = tid & 63;
  const int wv = tid >> 6;          // 0 or 1
  const int brow = lane & 15;
  const int kg = lane >> 4;

  int l, jt, mtile, kh;
  if (wg < 50)       { l = 0; jt = wg >> 1; mtile = (wg & 1) * 2 + wv; kh = 1; }
  else if (wg < 150) { int q = wg - 50;  l = 1; mtile = q & 3; jt = q >> 2; kh = wv; }
  else               { int q = wg - 150; l = 2; mtile = q & 3; jt = q >> 2; kh = wv; }
  const int jh = jt * 16 + brow;
  const bool selfw = (l == 0) || (kh == 1);
  if (selfw) __builtin_amdgcn_s_setprio(1);    // favor critical waves

  const u16* pk = (l == 0) ? &g_pk0[0][0][0] : (l == 1 ? &g_pk1[0][0][0] : &g_pk2[0][0][0]);
  const int nks = (l == 0) ? KS0 : KS12;
  const int wks0 = (l == 0) ? 0 : kh * 13;

  bf16x8 Bf[4][13];
#pragma unroll
  for (int g = 0; g < 4; ++g)
#pragma unroll
    for (int j = 0; j < 13; ++j)
      Bf[g][j] = *(const bf16x8*)&pk[(((g * 25 + jt) * nks + wks0 + j) * 64 + lane) * 8];

  float bsum[4], wxc[4][3];
#pragma unroll
  for (int g = 0; g < 4; ++g) {
    int n = g * 400 + jh;
    bsum[g] = g_bsum[l][n];
    wxc[g][0] = g_wx[l][n][0];
    wxc[g][1] = g_wx[l][n][1];
    wxc[g][2] = g_wx[l][n][2];
  }
  float cst[4] = {0.f, 0.f, 0.f, 0.f};

  __shared__ float red[2][2][64][20];   // [parity][kh][lane][16+pad]
  __shared__ int s_ab[2][2];

#define GLS(i, OFF) asm volatile("global_load_dwordx4 %0, %1, off offset:" OFF " sc1" \
                                 : "=v"(A[i]) : "v"(rowp))
#define GLS_ALL GLS(0,"0");GLS(1,"64");GLS(2,"128");GLS(3,"192");GLS(4,"256");GLS(5,"320"); \
                GLS(6,"384");GLS(7,"448");GLS(8,"512");GLS(9,"576");GLS(10,"640");          \
                GLS(11,"704");GLS(12,"768")
#define XGATE(xg) { \
  _Pragma("unroll") \
  for (int r = 0; r < 4; ++r) { \
    int row = mtile * 16 + kg * 4 + r; \
    const float* xp = X + ((long)row * TT + t) * 3; \
    float x0 = xp[0], x1 = xp[1], x2 = xp[2]; \
    _Pragma("unroll") \
    for (int g = 0; g < 4; ++g) \
      xg[g][r] = bsum[g] + wxc[g][0] * x0 + wxc[g][1] * x1 + wxc[g][2] * x2; \
  } }
#define MFMA_ALL { asm volatile("s_waitcnt vmcnt(0)" ::: "memory"); \
  __builtin_amdgcn_sched_barrier(0); \
  _Pragma("unroll") \
  for (int j = 0; j < 13; ++j) \
    _Pragma("unroll") \
    for (int g = 0; g < 4; ++g) \
      acc[g] = __builtin_amdgcn_mfma_f32_16x16x32_bf16(A[j], Bf[g][j], acc[g], 0, 0, 0); }

  if (l == 0) {
    // ===== layer 0: autonomous waves; outs-drain + fo publish deferred =====
    for (int t = 0; t < TT; ++t) {
      float xg[4][4];
      XGATE(xg);
      f32x4 acc[4] = {};
      if (t > 0) {
        if (wait_line<0>(g_f[0][mtile], t, jt)) return;
        // wait's vmcnt(0) drained outs(t-1) stores -> certify rows 0..t-1
        if (lane == 0) st32_s(&g_fo[0][mtile][jt][0], t);
        const u16* rowp = &g_h[0][(t - 1) & 1][mtile * 16 + brow][kg * 8];
        bf16x8 A[13];
        GLS_ALL;
        MFMA_ALL;
      }
      unsigned hb[4];
#pragma unroll
      for (int r = 0; r < 4; ++r) {
        float gate[4];
#pragma unroll
        for (int g = 0; g < 4; ++g) gate[g] = acc[g][r] + xg[g][r];
        float ig = sigm(gate[0]), fg = sigm(gate[1]);
        float gg = tanh_(gate[2]), og = sigm(gate[3]);
        float c = fg * cst[r] + ig * gg;
        cst[r] = c;
        hb[r] = (unsigned)f2b(og * tanh_(c));
        st16_s(&g_h[0][t & 1][mtile * 16 + kg * 4 + r][jh], hb[r]);
      }
      asm volatile("s_waitcnt vmcnt(0)" ::: "memory");   // h stores acked
      if (lane == 0) st32_s(&g_f[0][mtile][jt][0], t + 1);
      // outs stores: fire-and-forget (drained by next iteration's wait)
#pragma unroll
      for (int r = 0; r < 4; ++r)
        st16_s(&g_outs[(long)(mtile * 16 + kg * 4 + r) * TT + t][jh], hb[r]);
    }
    asm volatile("s_waitcnt vmcnt(0)" ::: "memory");
    if (lane == 0) st32_s(&g_fo[0][mtile][jt][0], TT);
    return;
  }

  // ===== layers 1/2: ONE pair per WG {kh=0 inter-wave, kh=1 self-wave} =====
  for (int t = 0; t < TT; ++t) {
    float xg[4][4];
    XGATE(xg);

    int ab = 0;
    f32x4 acc[4] = {};
    if (kh) {
      if (t > 0) {
        ab = wait_line<0>(g_f[l][mtile], t, jt);
        if (!ab) {
          const u16* rowp = &g_h[l][(t - 1) & 1][mtile * 16 + brow][kg * 8];
          bf16x8 A[13];
          GLS_ALL;
          MFMA_ALL;
        }
      }
    } else {
      ab = wait_line<1>(g_fo[l - 1][mtile], t + 1, -1);
      if (!ab) {
        // wait's vmcnt(0) drained own outs(t-1) stores -> certify (l==1 feeds l2)
        if (l == 1 && t > 0 && lane == 0) st32_s(&g_fo[1][mtile][jt][0], t);
        const u16* rowp = &g_outs[(long)(mtile * 16 + brow) * TT + t][(l - 1) * SEG + kg * 8];
        bf16x8 A[13];
        GLS_ALL;
        MFMA_ALL;
      }
    }
    if (lane == 0) s_ab[t & 1][wv] = ab;

    // deposit own partial; pair barrier; join with peer's
#pragma unroll
    for (int g = 0; g < 4; ++g)
      *(f32x4*)&red[t & 1][kh][lane][g * 4] = acc[g];
    __syncthreads();
    if (s_ab[t & 1][0] | s_ab[t & 1][1]) return;
    f32x4 gacc[4];
#pragma unroll
    for (int g = 0; g < 4; ++g)
      gacc[g] = acc[g] + *(const f32x4*)&red[t & 1][kh ^ 1][lane][g * 4];

    // epilogue duplicated on both waves (identical fp -> identical bits)
    unsigned hb[4];
#pragma unroll
    for (int r = 0; r < 4; ++r) {
      float gate[4];
#pragma unroll
      for (int g = 0; g < 4; ++g) gate[g] = gacc[g][r] + xg[g][r];
      float ig = sigm(gate[0]), fg = sigm(gate[1]);
      float gg = tanh_(gate[2]), og = sigm(gate[3]);
      float c = fg * cst[r] + ig * gg;
      cst[r] = c;
      hb[r] = (unsigned)f2b(og * tanh_(c));
    }

    if (kh) {
      // critical wave: h only, own drain, own flag slot
#pragma unroll
      for (int r = 0; r < 4; ++r)
        st16_s(&g_h[l][t & 1][mtile * 16 + kg * 4 + r][jh], hb[r]);
      asm volatile("s_waitcnt vmcnt(0)" ::: "memory");
      if (lane == 0) st32_s(&g_f[l][mtile][jt][0], t + 1);
    } else {
      // slack wave: outs stores fire-and-forget (drained by next wait's vmcnt)
#pragma unroll
      for (int r = 0; r < 4; ++r)
        st16_s(&g_outs[(long)(mtile * 16 + kg * 4 + r) * TT + t][l * SEG + jh], hb[r]);
    }
  }
  if (!kh && l == 1) {
    asm volatile("s_waitcnt vmcnt(0)" ::: "memory");
    if (lane == 0) st32_s(&g_fo[1][mtile][jt][0], TT);
  }
#undef GLS
#undef GLS_ALL
#undef XGATE
#undef MFMA_ALL
}

// ---------------- final projection: [65536,1248] x [1248,128] ----------------
__global__ __launch_bounds__(256) void k_final(float* __restrict__ out) {
  int mt   = blockIdx.x * 4 + (threadIdx.x >> 6);
  int lane = threadIdx.x & 63;
  int arow = mt * 16 + (lane & 15);
  int kchunk = (lane >> 4) * 8;
  f32x4 acc[8] = {};
  for (int ks = 0; ks < KSL; ++ks) {
    bf16x8 a = *(const bf16x8*)&g_outs[arow][ks * 32 + kchunk];
#pragma unroll
    for (int nt = 0; nt < 8; ++nt) {
      bf16x8 b = *(const bf16x8*)&g_pkl[nt][ks][lane * 8];
      acc[nt] = __builtin_amdgcn_mfma_f32_16x16x32_bf16(a, b, acc[nt], 0, 0, 0);
    }
  }
#pragma unroll
  for (int nt = 0; nt < 8; ++nt) {
    int o = nt * 16 + (lane & 15);
    if (o >= NOUT) continue;
#pragma unroll
    for (int r = 0; r < 4; ++r) {
      int m = mt * 16 + (lane >> 4) * 4 + r;
      out[(long)m * NOUT + o] = acc[nt][r] + g_bl[o];
    }
  }
}

// ---------------- launch ----------------
extern "C" void kernel_launch(void* const* d_in, const int* in_sizes, int n_in,
                              void* d_out, int out_size, void* d_ws, size_t ws_size,
                              hipStream_t stream) {
  const float* X    = (const float*)d_in[0];
  const float* Wih0 = (const float*)d_in[1];
  const float* Whh0 = (const float*)d_in[2];
  const float* bih0 = (const float*)d_in[3];
  const float* bhh0 = (const float*)d_in[4];
  const float* Wih1 = (const float*)d_in[5];
  const float* Whh1 = (const float*)d_in[6];
  const float* bih1 = (const float*)d_in[7];
  const float* bhh1 = (const float*)d_in[8];
  const float* Wih2 = (const float*)d_in[9];
  const float* Whh2 = (const float*)d_in[10];
  const float* bih2 = (const float*)d_in[11];
  const float* bhh2 = (const float*)d_in[12];
  const float* Wl   = (const float*)d_in[13];
  const float* bl   = (const float*)d_in[14];

  k_zero<<<(BB * TT * 24 + 255) / 256, 256, 0, stream>>>();
  k_pack_rec<<<(100 * KS0  * 512 + 255) / 256, 256, 0, stream>>>(nullptr, Whh0, 0, KS0, 3);
  k_pack_rec<<<(100 * KS12 * 512 + 255) / 256, 256, 0, stream>>>(Wih1, Whh1, 1, KS12, 403);
  k_pack_rec<<<(100 * KS12 * 512 + 255) / 256, 256, 0, stream>>>(Wih2, Whh2, 2, KS12, 403);
  k_pack_wl<<<(8 * KSL * 512 + 255) / 256, 256, 0, stream>>>(Wl, bl);
  k_pack_misc<<<(3 * G4 + 255) / 256, 256, 0, stream>>>(Wih0, bih0, bhh0,
                                                        Wih1, bih1, bhh1,
                                                        Wih2, bih2, bhh2);
  k_lstm<<<250, 128, 0, stream>>>(X);
  k_final<<<1024, 256, 0, stream>>>((float*)d_out);
}